// Round 2
// baseline (246.238 us; speedup 1.0000x reference)
//
#include <hip/hip_runtime.h>

// Problem: B=16, S=2048, D=1024, MAX_LEN=4096
// out[b,s,d] = x[b,s,d] + (keep[b,s] ? pe[rank[b,s], d] : 0)
// rank = cumsum(keep, axis=1) - 1  (keep = !mask; rank >= 0 wherever keep)

#define BB 16
#define SS 2048
#define DD 1024
#define D4 (DD / 4)                  // 256 float4 per row
#define TOTAL4 (BB * SS * D4)        // 8,388,608 float4

// Kernel 1: per-batch prefix sum over keep = !mask. One block per batch row.
// 256 threads x 8 elements = 2048 = S. Writes rank (>=0) or -1 sentinel.
// NOTE: harness uploads bool inputs as int32 ("integer -> const int*").
__global__ void __launch_bounds__(256)
ranks_kernel(const int* __restrict__ mask, int* __restrict__ ranks) {
    const int b = blockIdx.x;
    const int* m = mask + (size_t)b * SS;
    int* r = ranks + (size_t)b * SS;

    const int tid  = threadIdx.x;
    const int base = tid * 8;

    int vals[8];
    int sum = 0;
#pragma unroll
    for (int i = 0; i < 8; ++i) {
        int keep = (m[base + i] == 0) ? 1 : 0;   // keep = !mask
        vals[i] = keep;
        sum += keep;
    }

    // Inclusive scan of per-thread sums across the wave (width 64).
    const int lane = tid & 63;
    const int wid  = tid >> 6;
    int incl = sum;
#pragma unroll
    for (int off = 1; off < 64; off <<= 1) {
        int n = __shfl_up(incl, off, 64);
        if (lane >= off) incl += n;
    }

    __shared__ int wtot[4];
    if (lane == 63) wtot[wid] = incl;
    __syncthreads();

    int woff = 0;
    for (int w = 0; w < wid; ++w) woff += wtot[w];

    int run = woff + incl - sum;    // exclusive prefix for this thread's chunk
#pragma unroll
    for (int i = 0; i < 8; ++i) {
        run += vals[i];
        // keep position: rank = inclusive_cumsum - 1 >= 0; clip upper bound
        // unreachable (cumsum <= S). Masked position: -1 sentinel.
        r[base + i] = vals[i] ? (run - 1) : -1;
    }
}

// Kernel 2: out = x + (rank >= 0 ? pe[rank] : 0), float4-vectorized.
// idx -> (row = idx>>8, d4 = idx&255). rank is wave-uniform (64 lanes span a
// quarter of one row), so the branch doesn't diverge and pe reads coalesce.
__global__ void __launch_bounds__(256)
add_pe_kernel(const float4* __restrict__ x, const float4* __restrict__ pe,
              const int* __restrict__ ranks, float4* __restrict__ out) {
    int idx = blockIdx.x * 256 + threadIdx.x;
    const int stride = gridDim.x * 256;
    for (; idx < TOTAL4; idx += stride) {
        const int d4 = idx & (D4 - 1);
        const int bs = idx >> 8;
        const int rank = ranks[bs];
        float4 v = x[idx];
        if (rank >= 0) {
            const float4 p = pe[rank * D4 + d4];
            v.x += p.x; v.y += p.y; v.z += p.z; v.w += p.w;
        }
        out[idx] = v;
    }
}

extern "C" void kernel_launch(void* const* d_in, const int* in_sizes, int n_in,
                              void* d_out, int out_size, void* d_ws, size_t ws_size,
                              hipStream_t stream) {
    const float* x    = (const float*)d_in[0];
    const int*   mask = (const int*)d_in[1];   // bool uploaded as int32
    const float* pe   = (const float*)d_in[2];
    float*       out  = (float*)d_out;
    int*         ranks = (int*)d_ws;           // B*S ints = 128 KiB scratch

    ranks_kernel<<<BB, 256, 0, stream>>>(mask, ranks);

    // Grid-stride: 2048 blocks x 256 threads, 16 float4 per thread.
    add_pe_kernel<<<2048, 256, 0, stream>>>(
        (const float4*)x, (const float4*)pe, ranks, (float4*)out);
}

// Round 3
// 233.722 us; speedup vs baseline: 1.0536x; 1.0536x over previous
//
#include <hip/hip_runtime.h>

// Problem: B=16, S=2048, D=1024, MAX_LEN=4096
// out[b,s,d] = x[b,s,d] + (keep[b,s] ? pe[rank[b,s], d] : 0)
// rank = cumsum(keep, axis=1) - 1  (keep = !mask; rank >= 0 wherever keep)

#define BB 16
#define SS 2048
#define DD 1024
#define D4 (DD / 4)                  // 256 float4 per row
#define NROWS (BB * SS)              // 32768 rows
#define ROWS_PER_BLK 4

typedef float f4 __attribute__((ext_vector_type(4)));

// Kernel 1: per-batch prefix sum over keep = !mask. One block per batch row.
// 256 threads x 8 elements = 2048 = S. Writes rank (>=0) or -1 sentinel.
// Harness uploads bool inputs as int32.
__global__ void __launch_bounds__(256)
ranks_kernel(const int* __restrict__ mask, int* __restrict__ ranks) {
    const int b = blockIdx.x;
    const int* m = mask + (size_t)b * SS;
    int* r = ranks + (size_t)b * SS;

    const int tid  = threadIdx.x;
    const int base = tid * 8;

    int vals[8];
    int sum = 0;
#pragma unroll
    for (int i = 0; i < 8; ++i) {
        int keep = (m[base + i] == 0) ? 1 : 0;   // keep = !mask
        vals[i] = keep;
        sum += keep;
    }

    // Inclusive scan of per-thread sums across the wave (width 64).
    const int lane = tid & 63;
    const int wid  = tid >> 6;
    int incl = sum;
#pragma unroll
    for (int off = 1; off < 64; off <<= 1) {
        int n = __shfl_up(incl, off, 64);
        if (lane >= off) incl += n;
    }

    __shared__ int wtot[4];
    if (lane == 63) wtot[wid] = incl;
    __syncthreads();

    int woff = 0;
    for (int w = 0; w < wid; ++w) woff += wtot[w];

    int run = woff + incl - sum;    // exclusive prefix for this thread's chunk
#pragma unroll
    for (int i = 0; i < 8; ++i) {
        run += vals[i];
        r[base + i] = vals[i] ? (run - 1) : -1;  // -1 sentinel where masked
    }
}

// Kernel 2: 4 rows per block, 256 threads = one float4 column per row.
// All 4 ranks fetched in one int4; 4 independent load/add/store chains for
// memory-level parallelism. rank branch is block-uniform (no divergence).
__global__ void __launch_bounds__(256)
add_pe_kernel(const f4* __restrict__ x, const f4* __restrict__ pe,
              const int* __restrict__ ranks, f4* __restrict__ out) {
    const int row0 = blockIdx.x * ROWS_PER_BLK;
    const int t    = threadIdx.x;                 // d4 index 0..255
    const int4 rk  = *reinterpret_cast<const int4*>(ranks + row0);
    const size_t base = (size_t)row0 * D4 + t;

    f4 v0 = __builtin_nontemporal_load(&x[base]);
    f4 v1 = __builtin_nontemporal_load(&x[base + D4]);
    f4 v2 = __builtin_nontemporal_load(&x[base + 2 * D4]);
    f4 v3 = __builtin_nontemporal_load(&x[base + 3 * D4]);

    if (rk.x >= 0) v0 += pe[rk.x * D4 + t];
    if (rk.y >= 0) v1 += pe[rk.y * D4 + t];
    if (rk.z >= 0) v2 += pe[rk.z * D4 + t];
    if (rk.w >= 0) v3 += pe[rk.w * D4 + t];

    __builtin_nontemporal_store(v0, &out[base]);
    __builtin_nontemporal_store(v1, &out[base + D4]);
    __builtin_nontemporal_store(v2, &out[base + 2 * D4]);
    __builtin_nontemporal_store(v3, &out[base + 3 * D4]);
}

extern "C" void kernel_launch(void* const* d_in, const int* in_sizes, int n_in,
                              void* d_out, int out_size, void* d_ws, size_t ws_size,
                              hipStream_t stream) {
    const float* x    = (const float*)d_in[0];
    const int*   mask = (const int*)d_in[1];   // bool uploaded as int32
    const float* pe   = (const float*)d_in[2];
    float*       out  = (float*)d_out;
    int*         ranks = (int*)d_ws;           // B*S ints = 128 KiB scratch

    ranks_kernel<<<BB, 256, 0, stream>>>(mask, ranks);

    add_pe_kernel<<<NROWS / ROWS_PER_BLK, 256, 0, stream>>>(
        (const f4*)x, (const f4*)pe, ranks, (f4*)out);
}